// Round 8
// baseline (417.878 us; speedup 1.0000x reference)
//
#include <hip/hip_runtime.h>

#define BB    32
#define NSEQ  1024
#define CDIM  768
#define NH    12
#define HD    64
#define LKEYS 128
#define NPOOL 128

typedef __bf16 bf16x8 __attribute__((ext_vector_type(8)));
typedef float  f32x4  __attribute__((ext_vector_type(4)));

__device__ __forceinline__ ushort f2bf(float f) {
    union { float f; uint u; } v; v.f = f;
    uint u = v.u;
    uint r = u + 0x7FFFu + ((u >> 16) & 1u);   // RNE
    return (ushort)(r >> 16);
}
__device__ __forceinline__ uint pack2(float x, float y) {
    return (uint)f2bf(x) | ((uint)f2bf(y) << 16);
}
// packed f32->bf16 via HW (RNE, same rounding as f2bf; T12 primitive)
__device__ __forceinline__ uint cvtpk(float lo, float hi) {
    uint u;
    asm("v_cvt_pk_bf16_f32 %0, %1, %2" : "=v"(u) : "v"(lo), "v"(hi));
    return u;
}

// ---------------------------------------------------------------------------
// 0) prep (R7-verbatim, passed): z=0 transpose Wqkv, z=1 transpose Wproj,
//    z=2 pool. One launch, dim3(72,24,3).
// ---------------------------------------------------------------------------
__global__ __launch_bounds__(256) void prep_kernel(
    const float* __restrict__ Wqkv, ushort* __restrict__ Wq_t,
    const float* __restrict__ Wproj, ushort* __restrict__ Wp_t,
    const float* __restrict__ x, ushort* __restrict__ xp)
{
    __shared__ ushort tile[32][33];
    int z = blockIdx.z;

    if (z == 2) {
        int flatb = blockIdx.y * 72 + blockIdx.x;
        if (flatb >= 1536) return;
        int idx = flatb * 256 + threadIdx.x;        // over B*128*96
        int c8 = idx % 96;
        int t  = idx / 96;
        int i  = t % NPOOL;
        int b  = t / NPOOL;
        if (b >= BB) return;
        const float4* x4 = (const float4*)x;
        size_t base0 = ((size_t)(b * NSEQ + 2 * i)) * 192 + c8 * 2;
        size_t base1 = base0 + 192;
        float4 a0 = x4[base0], a1 = x4[base0 + 1];
        float4 b0 = x4[base1], b1 = x4[base1 + 1];
        uint4 o;
        o.x = pack2(0.5f * (a0.x + b0.x), 0.5f * (a0.y + b0.y));
        o.y = pack2(0.5f * (a0.z + b0.z), 0.5f * (a0.w + b0.w));
        o.z = pack2(0.5f * (a1.x + b1.x), 0.5f * (a1.y + b1.y));
        o.w = pack2(0.5f * (a1.z + b1.z), 0.5f * (a1.w + b1.w));
        ((uint4*)xp)[idx] = o;
        return;
    }

    if (z == 1 && blockIdx.x >= 24) return;
    const float* src = z ? Wproj : Wqkv;
    ushort* dst      = z ? Wp_t  : Wq_t;
    int C = z ? CDIM : 3 * CDIM;
    const int R = CDIM;

    int bc = blockIdx.x * 32, br = blockIdx.y * 32;
    int tx = threadIdx.x & 31, ty = threadIdx.x >> 5;
#pragma unroll
    for (int i = 0; i < 32; i += 8)
        tile[ty + i][tx] = f2bf(src[(size_t)(br + ty + i) * C + bc + tx]);
    __syncthreads();
#pragma unroll
    for (int i = 0; i < 32; i += 8)
        dst[(size_t)(bc + ty + i) * R + br + tx] = tile[tx][ty + i];
}

// ---------------------------------------------------------------------------
// 1) fused Q + KV projection (R6 device code, workspace bug was external).
//    blocks [0,1536):  Q  = x(f32, gload_lds-staged) @ Wq_t[0:768]^T  -> bf16
//    blocks [1536,1920): KV = xp(bf16) @ Wq_t[768:2304]^T             -> fp32
//    m97 structure (BK=32), XOR chunk swizzle both-sides; fp32 A converts to
//    bf16 at ds_read time via v_cvt_pk_bf16_f32 (RNE).
// ---------------------------------------------------------------------------
__global__ __launch_bounds__(256) void qkv_kernel(
    const float* __restrict__ x, const ushort* __restrict__ xp,
    const ushort* __restrict__ Wq_t, const float* __restrict__ bqkv,
    ushort* __restrict__ qb, float* __restrict__ kvp)
{
    __shared__ __align__(16) unsigned char smem[24 * 1024];

    int tid = threadIdx.x, wave = tid >> 6, lane = tid & 63;
    int wm = wave >> 1, wn = wave & 1;
    int lm = lane & 15, lh = lane >> 4;

    // XCD swizzle over 1920 blocks (1920 % 8 == 0 -> simple bijective form)
    int bid0 = blockIdx.x;
    int cpx  = gridDim.x >> 3;
    int bid  = (bid0 & 7) * cpx + (bid0 >> 3);

    f32x4 acc[4][4] = {};

    if (bid < 1536) {
        // ---------------- Q part ----------------
        float*  As = (float*)smem;                 // [128][32] f32 (16 KB)
        ushort* Bs = (ushort*)(smem + 16384);      // [128][32] bf16 (8 KB)
        int n0 = (bid % 6) * 128, m0 = (bid / 6) * 128;

        for (int k0 = 0; k0 < CDIM; k0 += 32) {
            __syncthreads();
#pragma unroll
            for (int ld = 0; ld < 4; ld++) {       // A: 1024 x 16B chunks
                int fl = ld * 256 + tid;
                int row = fl >> 3, pch = fl & 7;
                int lch = pch ^ (row & 7);
                const float* g = x + (size_t)(m0 + row) * CDIM + k0 + lch * 4;
                __builtin_amdgcn_global_load_lds(
                    (const __attribute__((address_space(1))) void*)g,
                    (__attribute__((address_space(3))) void*)(As + fl * 4),
                    16, 0, 0);
            }
#pragma unroll
            for (int ld = 0; ld < 2; ld++) {       // B: 512 x 16B chunks
                int fl = ld * 256 + tid;
                int row = fl >> 2, pch = fl & 3;
                int lch = pch ^ (row & 3);
                const ushort* g = Wq_t + (size_t)(n0 + row) * CDIM + k0 + lch * 8;
                __builtin_amdgcn_global_load_lds(
                    (const __attribute__((address_space(1))) void*)g,
                    (__attribute__((address_space(3))) void*)(Bs + fl * 8),
                    16, 0, 0);
            }
            __syncthreads();

            bf16x8 af[4], bfr[4];
#pragma unroll
            for (int jj = 0; jj < 4; jj++) {
                int rn = wn * 64 + jj * 16 + lm;
                bfr[jj] = *(const bf16x8*)((const void*)&Bs[rn * 32 + ((lh ^ (rn & 3)) * 8)]);
            }
#pragma unroll
            for (int i = 0; i < 4; i++) {
                int rm = wm * 64 + i * 16 + lm;
                int s = rm & 7;
                float4 fa = *(const float4*)&As[rm * 32 + (((2 * lh)     ^ s) * 4)];
                float4 fb = *(const float4*)&As[rm * 32 + (((2 * lh + 1) ^ s) * 4)];
                uint4 u;
                u.x = cvtpk(fa.x, fa.y); u.y = cvtpk(fa.z, fa.w);
                u.z = cvtpk(fb.x, fb.y); u.w = cvtpk(fb.z, fb.w);
                af[i] = *(const bf16x8*)((const void*)&u);
            }
#pragma unroll
            for (int i = 0; i < 4; i++)
#pragma unroll
                for (int jj = 0; jj < 4; jj++)
                    acc[i][jj] = __builtin_amdgcn_mfma_f32_16x16x32_bf16(af[i], bfr[jj], acc[i][jj], 0, 0, 0);
        }

        int crow = m0 + wm * 64, ccol = n0 + wn * 64;
#pragma unroll
        for (int jj = 0; jj < 4; jj++) {
            int col = ccol + jj * 16 + lm;
            float bb = bqkv[col];
#pragma unroll
            for (int i = 0; i < 4; i++)
#pragma unroll
                for (int rr = 0; rr < 4; rr++)
                    qb[(size_t)(crow + i * 16 + lh * 4 + rr) * CDIM + col] = f2bf(acc[i][jj][rr] + bb);
        }
    } else {
        // ---------------- KV part ----------------
        ushort* As = (ushort*)smem;                // [128][32] bf16 (8 KB)
        ushort* Bs = (ushort*)(smem + 8192);       // [128][32] bf16 (8 KB)
        int b2 = bid - 1536;
        int n0 = (b2 % 12) * 128, m0 = (b2 / 12) * 128;
        const ushort* Bt = Wq_t + (size_t)CDIM * CDIM;   // rows 768..2303
        const int NKV = 2 * CDIM;

        for (int k0 = 0; k0 < CDIM; k0 += 32) {
            __syncthreads();
#pragma unroll
            for (int ld = 0; ld < 2; ld++) {
                int fl = ld * 256 + tid;
                int row = fl >> 2, pch = fl & 3;
                int lch = pch ^ (row & 3);
                const ushort* gA = xp + (size_t)(m0 + row) * CDIM + k0 + lch * 8;
                const ushort* gB = Bt + (size_t)(n0 + row) * CDIM + k0 + lch * 8;
                __builtin_amdgcn_global_load_lds(
                    (const __attribute__((address_space(1))) void*)gA,
                    (__attribute__((address_space(3))) void*)(As + fl * 8),
                    16, 0, 0);
                __builtin_amdgcn_global_load_lds(
                    (const __attribute__((address_space(1))) void*)gB,
                    (__attribute__((address_space(3))) void*)(Bs + fl * 8),
                    16, 0, 0);
            }
            __syncthreads();

            bf16x8 af[4], bfr[4];
#pragma unroll
            for (int jj = 0; jj < 4; jj++) {
                int rn = wn * 64 + jj * 16 + lm;
                bfr[jj] = *(const bf16x8*)((const void*)&Bs[rn * 32 + ((lh ^ (rn & 3)) * 8)]);
            }
#pragma unroll
            for (int i = 0; i < 4; i++) {
                int rm = wm * 64 + i * 16 + lm;
                af[i] = *(const bf16x8*)((const void*)&As[rm * 32 + ((lh ^ (rm & 3)) * 8)]);
            }
#pragma unroll
            for (int i = 0; i < 4; i++)
#pragma unroll
                for (int jj = 0; jj < 4; jj++)
                    acc[i][jj] = __builtin_amdgcn_mfma_f32_16x16x32_bf16(af[i], bfr[jj], acc[i][jj], 0, 0, 0);
        }

        int crow = m0 + wm * 64, ccol = n0 + wn * 64;
#pragma unroll
        for (int jj = 0; jj < 4; jj++) {
            int col = ccol + jj * 16 + lm;
            float bb = bqkv[CDIM + col];
#pragma unroll
            for (int i = 0; i < 4; i++)
#pragma unroll
                for (int rr = 0; rr < 4; rr++)
                    kvp[(size_t)(crow + i * 16 + lh * 4 + rr) * NKV + col] = acc[i][jj][rr] + bb;
        }
    }
}

// ---------------------------------------------------------------------------
// 2) 128x128-tile BK=64 double-buffered GEMM (R7-verbatim, 58.6 µs measured)
//    — out-proj only.
// ---------------------------------------------------------------------------
template <bool OBF16>
__global__ __launch_bounds__(256) void gemm_db_kernel(
    const ushort* __restrict__ A, const ushort* __restrict__ Bt,
    const float* __restrict__ bias, void* __restrict__ Cout,
    int M, int N, int K)
{
    __shared__ ushort As[2][128 * 64];   // 2 x 16 KB
    __shared__ ushort Bs[2][128 * 64];   // 2 x 16 KB

    int tid  = threadIdx.x;
    int lane = tid & 63;
    int wave = tid >> 6;

    int nwg  = gridDim.x * gridDim.y;
    int bid  = blockIdx.y * gridDim.x + blockIdx.x;
    int q    = nwg >> 3, r = nwg & 7;
    int xcd  = bid & 7, jj0 = bid >> 3;
    int flat = (xcd < r ? xcd * (q + 1) : r * (q + 1) + (xcd - r) * q) + jj0;
    int n0 = (flat % gridDim.x) * 128;
    int m0 = (flat / gridDim.x) * 128;

    int wm = wave >> 1, wn = wave & 1;
    int lm = lane & 15, lh = lane >> 4;

    const int NT = K >> 6;

    auto stageB = [&](int tt) {
        int slot = tt & 1;
#pragma unroll
        for (int ld = 0; ld < 4; ld++) {
            int c = ld * 256 + tid;
            int prow = c >> 3, pch = c & 7;
            int lch = pch ^ (prow & 7);
            const ushort* g = Bt + (size_t)(n0 + prow) * K + tt * 64 + lch * 8;
            __builtin_amdgcn_global_load_lds(
                (const __attribute__((address_space(1))) void*)g,
                (__attribute__((address_space(3))) void*)(&Bs[slot][c * 8]),
                16, 0, 0);
        }
    };
    auto stageA16 = [&](int tt) {
        int slot = tt & 1;
#pragma unroll
        for (int ld = 0; ld < 4; ld++) {
            int c = ld * 256 + tid;
            int prow = c >> 3, pch = c & 7;
            int lch = pch ^ (prow & 7);
            const ushort* g = A + (size_t)(m0 + prow) * K + tt * 64 + lch * 8;
            __builtin_amdgcn_global_load_lds(
                (const __attribute__((address_space(1))) void*)g,
                (__attribute__((address_space(3))) void*)(&As[slot][c * 8]),
                16, 0, 0);
        }
    };

    f32x4 acc[4][4] = {};

    auto compute = [&](int slot) {
        bf16x8 bfr[4], af[4];
#pragma unroll
        for (int ks = 0; ks < 2; ks++) {
#pragma unroll
            for (int jj = 0; jj < 4; jj++) {
                int rn = wn * 64 + jj * 16 + lm;
                int ch = (ks * 4 + lh) ^ (rn & 7);
                bfr[jj] = *(const bf16x8*)((const void*)&Bs[slot][rn * 64 + ch * 8]);
            }
#pragma unroll
            for (int i = 0; i < 4; i++) {
                int rm = wm * 64 + i * 16 + lm;
                int ch = (ks * 4 + lh) ^ (rm & 7);
                af[i] = *(const bf16x8*)((const void*)&As[slot][rm * 64 + ch * 8]);
            }
            __builtin_amdgcn_s_setprio(1);
#pragma unroll
            for (int i = 0; i < 4; i++)
#pragma unroll
                for (int jj = 0; jj < 4; jj++)
                    acc[i][jj] = __builtin_amdgcn_mfma_f32_16x16x32_bf16(af[i], bfr[jj], acc[i][jj], 0, 0, 0);
            __builtin_amdgcn_s_setprio(0);
        }
    };

    stageA16(0); stageB(0);
    stageA16(1); stageB(1);
    for (int t = 0; t < NT; t++) {
        int slot = t & 1;
        if (t + 1 < NT) asm volatile("s_waitcnt vmcnt(8)" ::: "memory");
        else            asm volatile("s_waitcnt vmcnt(0)" ::: "memory");
        __builtin_amdgcn_s_barrier();
        asm volatile("" ::: "memory");
        compute(slot);
        __builtin_amdgcn_s_barrier();
        asm volatile("" ::: "memory");
        if (t + 2 < NT) { stageA16(t + 2); stageB(t + 2); }
    }

    int crow = m0 + wm * 64, ccol = n0 + wn * 64;
#pragma unroll
    for (int jj = 0; jj < 4; jj++) {
        int col = ccol + jj * 16 + lm;
        float bb = bias[col];
        if constexpr (OBF16) {
            ushort* C = (ushort*)Cout;
#pragma unroll
            for (int i = 0; i < 4; i++)
#pragma unroll
                for (int rr = 0; rr < 4; rr++)
                    C[(size_t)(crow + i * 16 + lh * 4 + rr) * N + col] = f2bf(acc[i][jj][rr] + bb);
        } else {
            float* C = (float*)Cout;
#pragma unroll
            for (int i = 0; i < 4; i++)
#pragma unroll
                for (int rr = 0; rr < 4; rr++)
                    C[(size_t)(crow + i * 16 + lh * 4 + rr) * N + col] = acc[i][jj][rr] + bb;
        }
    }
}

// ---------------------------------------------------------------------------
// 3) compress + bank assembly (R7-verbatim)
// ---------------------------------------------------------------------------
__global__ __launch_bounds__(256) void compress_kernel(
    const float* __restrict__ kvp,
    const float* __restrict__ Ek, const float* __restrict__ Ev,
    const float* __restrict__ kbank, const float* __restrict__ vbank,
    ushort* __restrict__ kfull, ushort* __restrict__ vfullT)
{
    __shared__ float Es[128 * 64];
    __shared__ float Sl[128 * 64];

    int tid = threadIdx.x;
    int h = blockIdx.x, b = blockIdx.y, which = blockIdx.z;
    const float* E    = which ? Ev : Ek;
    const float* bank = which ? vbank : kbank;

#pragma unroll
    for (int i = 0; i < 8; i++) {
        int flat = tid + i * 256;
        *(float4*)&Es[flat * 4] = *(const float4*)&E[flat * 4];
    }
    const float* src = kvp + (size_t)b * 128 * 1536 + which * 768 + h * HD;
#pragma unroll
    for (int i = 0; i < 8; i++) {
        int flat = tid + i * 256;
        int s = flat >> 4, d4 = flat & 15;
        *(float4*)&Sl[s * 64 + d4 * 4] = *(const float4*)&src[(size_t)s * 1536 + d4 * 4];
    }

    const float* bankbase = bank + (size_t)b * 64 * CDIM + h * HD;
    ushort* outK = kfull  + (size_t)(b * NH + h) * LKEYS * HD;
    ushort* outV = vfullT + (size_t)(b * NH + h) * HD * LKEYS;

#pragma unroll
    for (int i = 0; i < 4; i++) {
        int flat = tid + i * 256;
        int j = flat >> 4, d4 = flat & 15;
        float4 v = *(const float4*)&bankbase[(size_t)j * CDIM + d4 * 4];
        if (!which) {
            ushort4 o;
            o.x = f2bf(v.x); o.y = f2bf(v.y); o.z = f2bf(v.z); o.w = f2bf(v.w);
            *(ushort4*)&outK[(size_t)(64 + j) * HD + d4 * 4] = o;
        } else {
            outV[(size_t)(d4 * 4 + 0) * LKEYS + 64 + j] = f2bf(v.x);
            outV[(size_t)(d4 * 4 + 1) * LKEYS + 64 + j] = f2bf(v.y);
            outV[(size_t)(d4 * 4 + 2) * LKEYS + 64 + j] = f2bf(v.z);
            outV[(size_t)(d4 * 4 + 3) * LKEYS + 64 + j] = f2bf(v.w);
        }
    }
    __syncthreads();

    int tx = tid & 15, ty = tid >> 4;
    float acc[4][4];
#pragma unroll
    for (int i = 0; i < 4; i++)
#pragma unroll
        for (int j = 0; j < 4; j++) acc[i][j] = 0.f;

#pragma unroll 4
    for (int s = 0; s < 128; s++) {
        float4 av = *(const float4*)&Es[s * 64 + ty * 4];
        float4 bv = *(const float4*)&Sl[s * 64 + tx * 4];
        float a[4] = {av.x, av.y, av.z, av.w};
        float bb[4] = {bv.x, bv.y, bv.z, bv.w};
#pragma unroll
        for (int i = 0; i < 4; i++)
#pragma unroll
            for (int j = 0; j < 4; j++)
                acc[i][j] += a[i] * bb[j];
    }
    if (!which) {
#pragma unroll
        for (int i = 0; i < 4; i++) {
            ushort4 o;
            o.x = f2bf(acc[i][0]); o.y = f2bf(acc[i][1]);
            o.z = f2bf(acc[i][2]); o.w = f2bf(acc[i][3]);
            *(ushort4*)&outK[(size_t)(ty * 4 + i) * HD + tx * 4] = o;
        }
    } else {
#pragma unroll
        for (int i = 0; i < 4; i++)
#pragma unroll
            for (int j = 0; j < 4; j++)
                outV[(size_t)(tx * 4 + j) * LKEYS + ty * 4 + i] = f2bf(acc[i][j]);
    }
}

// ---------------------------------------------------------------------------
// 4) MFMA attention (R7-verbatim)
// ---------------------------------------------------------------------------
__global__ __launch_bounds__(256) void attn_mfma_kernel(
    const ushort* __restrict__ qb, const ushort* __restrict__ kf,
    const ushort* __restrict__ vt, ushort* __restrict__ ob)
{
    __shared__ __align__(16) ushort lds[64 * 72 + 128 * 72 + 64 * 136];
    ushort* Qs = lds;
    ushort* Ks = lds + 64 * 72;
    ushort* Vs = lds + 64 * 72 + 128 * 72;
    ushort* Ps = lds;

    int tid  = threadIdx.x;
    int wave = tid >> 6, lane = tid & 63;
    int lm = lane & 15, lh = lane >> 4;
    int qt = blockIdx.x, h = blockIdx.y, b = blockIdx.z;

    const ushort* qbase = qb + ((size_t)(b * NSEQ + qt * 64)) * CDIM + h * HD;
    const ushort* kbase = kf + (size_t)(b * NH + h) * LKEYS * HD;
    const ushort* vbase = vt + (size_t)(b * NH + h) * HD * LKEYS;

#pragma unroll
    for (int it = 0; it < 2; it++) {
        int flat = tid + it * 256;
        int row = flat >> 3, seg = flat & 7;
        *(uint4*)&Qs[row * 72 + seg * 8] = *(const uint4*)&qbase[(size_t)row * CDIM + seg * 8];
    }
#pragma unroll
    for (int it = 0; it < 4; it++) {
        int flat = tid + it * 256;
        int row = flat >> 3, seg = flat & 7;
        *(uint4*)&Ks[row * 72 + seg * 8] = *(const uint4*)&kbase[(size_t)row * HD + seg * 8];
    }
#pragma unroll
    for (int it = 0; it < 4; it++) {
        int flat = tid + it * 256;
        int row = flat >> 4, seg = flat & 15;
        *(uint4*)&Vs[row * 136 + seg * 8] = *(const uint4*)&vbase[(size_t)row * LKEYS + seg * 8];
    }
    __syncthreads();

    f32x4 sacc[8] = {};
    bf16x8 aq[2];
#pragma unroll
    for (int ks = 0; ks < 2; ks++)
        aq[ks] = *(const bf16x8*)((const void*)&Qs[(wave * 16 + lm) * 72 + ks * 32 + lh * 8]);
#pragma unroll
    for (int j = 0; j < 8; j++)
#pragma unroll
        for (int ks = 0; ks < 2; ks++) {
            bf16x8 bk = *(const bf16x8*)((const void*)&Ks[(j * 16 + lm) * 72 + ks * 32 + lh * 8]);
            sacc[j] = __builtin_amdgcn_mfma_f32_16x16x32_bf16(aq[ks], bk, sacc[j], 0, 0, 0);
        }

    float rinv[4];
#pragma unroll
    for (int r = 0; r < 4; r++) {
        float m = sacc[0][r];
#pragma unroll
        for (int j = 1; j < 8; j++) m = fmaxf(m, sacc[j][r]);
#pragma unroll
        for (int off = 1; off < 16; off <<= 1) m = fmaxf(m, __shfl_xor(m, off, 64));
        float s = 0.f;
#pragma unroll
        for (int j = 0; j < 8; j++) {
            float e = __expf((sacc[j][r] - m) * 0.125f);
            sacc[j][r] = e;
            s += e;
        }
#pragma unroll
        for (int off = 1; off < 16; off <<= 1) s += __shfl_xor(s, off, 64);
        rinv[r] = 1.f / s;
    }

    __syncthreads();
#pragma unroll
    for (int j = 0; j < 8; j++)
#pragma unroll
        for (int r = 0; r < 4; r++)
            Ps[(size_t)(wave * 16 + lh * 4 + r) * 136 + j * 16 + lm] = f2bf(sacc[j][r] * rinv[r]);
    __syncthreads();

    f32x4 oacc[4] = {};
#pragma unroll
    for (int ks = 0; ks < 4; ks++) {
        bf16x8 ap = *(const bf16x8*)((const void*)&Ps[(wave * 16 + lm) * 136 + ks * 32 + lh * 8]);
#pragma unroll
        for (int j = 0; j < 4; j++) {
            bf16x8 bv = *(const bf16x8*)((const void*)&Vs[(j * 16 + lm) * 136 + ks * 32 + lh * 8]);
            oacc[j] = __builtin_amdgcn_mfma_f32_16x16x32_bf16(ap, bv, oacc[j], 0, 0, 0);
        }
    }

    ushort* obase = ob + ((size_t)(b * NSEQ + qt * 64)) * CDIM + h * HD;
#pragma unroll
    for (int j = 0; j < 4; j++)
#pragma unroll
        for (int r = 0; r < 4; r++)
            obase[(size_t)(wave * 16 + lh * 4 + r) * CDIM + j * 16 + lm] = f2bf(oacc[j][r]);
}

// ---------------------------------------------------------------------------
// launch — 5 dispatches: prep -> qkv -> compress -> attn -> out-proj
// ---------------------------------------------------------------------------
extern "C" void kernel_launch(void* const* d_in, const int* in_sizes, int n_in,
                              void* d_out, int out_size, void* d_ws, size_t ws_size,
                              hipStream_t stream)
{
    const float* x     = (const float*)d_in[0];
    const float* Wqkv  = (const float*)d_in[1];
    const float* bqkv  = (const float*)d_in[2];
    const float* Ek    = (const float*)d_in[3];
    const float* Ev    = (const float*)d_in[4];
    const float* Wproj = (const float*)d_in[5];
    const float* bproj = (const float*)d_in[6];
    const float* kbank = (const float*)d_in[7];
    const float* vbank = (const float*)d_in[8];
    float* out = (float*)d_out;
    float* ws  = (float*)d_ws;

    // workspace (float units) — FIXED sizes (R6's bug: k_full/v_fullT are
    // 3,145,728 ushorts = 1,572,864 FLOATS each; R6 spaced them by 786,432 f).
    float*  kvp    = ws;                              // [0,        6291456)  f
    ushort* qb_bf  = (ushort*)(ws + 6291456);         // [6291456, 18874368)  f
    ushort* aob    = (ushort*)(ws + 18874368);        // [18874368,31457280)  f
    ushort* xp_bf  = (ushort*)(ws + 31457280);        // [31457280,33030144)  f
    ushort* Wq_t   = (ushort*)(ws + 33030144);        // [33030144,33914880)  f
    ushort* Wp_t   = (ushort*)(ws + 33914880);        // [33914880,34209792)  f
    ushort* k_full = (ushort*)(ws + 34209792);        // [34209792,35782656)  f
    ushort* v_fullT= (ushort*)(ws + 35782656);        // [35782656,37355520)  f

    prep_kernel<<<dim3(72, 24, 3), 256, 0, stream>>>(Wqkv, Wq_t, Wproj, Wp_t, x, xp_bf);

    // fused Q (1536 blocks) + KV (384 blocks) projections
    qkv_kernel<<<1920, 256, 0, stream>>>(x, xp_bf, Wq_t, bqkv, qb_bf, kvp);

    compress_kernel<<<dim3(NH, BB, 2), 256, 0, stream>>>(
        kvp, Ek, Ev, kbank, vbank, k_full, v_fullT);

    attn_mfma_kernel<<<dim3(16, NH, BB), 256, 0, stream>>>(qb_bf, k_full, v_fullT, aob);

    // output projection (fp32 final out)
    gemm_db_kernel<false><<<dim3(6, 256), 256, 0, stream>>>(
        aob, Wp_t, bproj, out, BB * NSEQ, CDIM, CDIM);
}